// Round 4
// baseline (174.139 us; speedup 1.0000x reference)
//
#include <hip/hip_runtime.h>
#include <hip/hip_bf16.h>

typedef unsigned short u16;
typedef __bf16 bf16x8 __attribute__((ext_vector_type(8)));
typedef float floatx4 __attribute__((ext_vector_type(4)));

#define SB 4
#define ST 1024
#define SC 1024
#define SH 16
#define SD 64

__device__ __forceinline__ u16 f2bf(float f) {
    unsigned int u = __builtin_bit_cast(unsigned int, f);
    u += 0x7fffu + ((u >> 16) & 1u);   // RNE
    return (u16)(u >> 16);
}

// async 16B/lane global->LDS (m97). LDS dest is wave-uniform base + lane*16.
__device__ __forceinline__ void gload16(const u16* g, u16* l) {
    __builtin_amdgcn_global_load_lds(
        (const __attribute__((address_space(1))) unsigned int*)g,
        (__attribute__((address_space(3))) unsigned int*)l, 16, 0, 0);
}

// ---- fused prep: x->bf16 | Wq/Wk/Wv -> Wqkv[n][c] | Wp -> Wpt[n][k] ----
__global__ void k_prep(const float* __restrict__ x,
                       const float* __restrict__ Wq, const float* __restrict__ Wk,
                       const float* __restrict__ Wv, const float* __restrict__ Wp,
                       u16* __restrict__ xb, u16* __restrict__ Wqkv, u16* __restrict__ Wpt) {
    __shared__ float tile[64 * 65];
    const int id = blockIdx.x, tid = threadIdx.x;
    if (id < 4096) {                               // x: fp32 -> bf16, float4 lanes
        int i = id * 256 + tid;
        float4 v = ((const float4*)x)[i];
        uint2 o;
        o.x = (unsigned)f2bf(v.x) | ((unsigned)f2bf(v.y) << 16);
        o.y = (unsigned)f2bf(v.z) | ((unsigned)f2bf(v.w) << 16);
        ((uint2*)xb)[i] = o;
    } else if (id < 4864) {                        // Wq/Wk/Wv transpose to [n][c]
        const int id1 = id - 4096;
        const int qkv = id1 >> 8, rem = id1 & 255, h = rem >> 4, c0 = (rem & 15) * 64;
        const float* src = qkv == 0 ? Wq : (qkv == 1 ? Wk : Wv);
        #pragma unroll
        for (int i = 0; i < 16; ++i) {
            int idx = tid + i * 256;
            int r = idx >> 6, d = idx & 63;
            tile[r * 65 + d] = src[(h * SC + c0 + r) * SD + d];
        }
        __syncthreads();
        #pragma unroll
        for (int i = 0; i < 16; ++i) {
            int idx = tid + i * 256;
            int d = idx >> 6, cc = idx & 63;
            Wqkv[(qkv * 1024 + h * SD + d) * SC + c0 + cc] = f2bf(tile[cc * 65 + d]);
        }
    } else {                                       // Wp transpose to [n][k]
        const int id2 = id - 4864;
        const int n0 = (id2 & 15) * 64, k0 = (id2 >> 4) * 64;
        #pragma unroll
        for (int i = 0; i < 16; ++i) {
            int idx = tid + i * 256;
            int r = idx >> 6, nn = idx & 63;
            tile[r * 65 + nn] = Wp[(k0 + r) * SC + n0 + nn];
        }
        __syncthreads();
        #pragma unroll
        for (int i = 0; i < 16; ++i) {
            int idx = tid + i * 256;
            int nr = idx >> 6, kk = idx & 63;
            Wpt[(n0 + nr) * (SH * SD) + k0 + kk] = f2bf(tile[kk * 65 + nr]);
        }
    }
}

// ---- QKV GEMM: 8-phase 256x256 schedule (m201 template, T3+T4+T5) ----
// BM=BN=256, BK=64, 512 thr = 8 waves (2M x 4N), wave tile 128x64.
// LDS 128KB: As/Bs[2buf][2half][128*64]. Per K-tile: 4 phases, each =
// {ds_read frags; stage 1 half-tile; barrier; 16 MFMA (setprio); barrier}.
// Stage stream during kt: q0:A0(kt+1) q1:A1(kt+1) -> buf^1 (WAR-safe);
// q2:B0(kt+2) q3:B1(kt+2) -> buf (safe: all B frags consumed in q0).
// vmcnt(4) once per K-tile (2 newest B half-tiles stay in flight across
// barriers = T4 counted wait). Prologue: 6 half-tiles, vmcnt(4).
// Swapped-operand MFMA -> D^T per-lane: m=l16, n=quad*4+r.
__launch_bounds__(512, 1)
__global__ void k_gemm(const u16* __restrict__ A, const u16* __restrict__ Bt,
                       u16* __restrict__ Qb, u16* __restrict__ Kb, u16* __restrict__ Vt) {
    constexpr int K = 1024;
    __shared__ u16 As[2][2][128 * 64];
    __shared__ u16 Bs[2][2][128 * 64];
    const int tid = threadIdx.x, lane = tid & 63, w = tid >> 6;
    const int quad = lane >> 4, l16 = lane & 15;
    const int sr = lane >> 3, sc = lane & 7;
    const int m0 = (blockIdx.x / 12) * 256, n0 = (blockIdx.x % 12) * 256;
    const int wm = (w >> 2) * 128, wn = (w & 3) * 64;
    const int ah = w >> 2;                          // this wave's A-half

    auto stA = [&](int buf, int half, int kt) {
        #pragma unroll
        for (int i = 0; i < 2; ++i) {
            int rb = (w * 2 + i) * 8;
            gload16(&A[(long)(m0 + half * 128 + rb + sr) * K + kt * 64 + ((sc ^ sr) << 3)],
                    &As[buf][half][rb * 64]);
        }
    };
    auto stB = [&](int buf, int half, int kt) {
        #pragma unroll
        for (int i = 0; i < 2; ++i) {
            int rb = (w * 2 + i) * 8;
            gload16(&Bt[(long)(n0 + half * 128 + rb + sr) * K + kt * 64 + ((sc ^ sr) << 3)],
                    &Bs[buf][half][rb * 64]);
        }
    };

    floatx4 acc[8][4] = {};
    // prologue stream: A0(0) A1(0) B0(0) B1(0) B0(1) B1(1)
    stA(0, 0, 0); stA(0, 1, 0); stB(0, 0, 0); stB(0, 1, 0); stB(1, 0, 1); stB(1, 1, 1);
    asm volatile("s_waitcnt vmcnt(4)" ::: "memory");
    __builtin_amdgcn_s_barrier();

    for (int kt = 0; kt < 16; ++kt) {
        const int buf = kt & 1;
        bf16x8 bfr[4][2];                           // lives across the 4 phases
        #pragma unroll
        for (int q = 0; q < 4; ++q) {
            if (q == 0) {                           // all B frags, once per K-tile
                #pragma unroll
                for (int nf = 0; nf < 4; ++nf) {
                    int bn = wn + nf * 16 + l16;
                    int bh = bn >> 7, r7 = bn & 127;
                    #pragma unroll
                    for (int ks = 0; ks < 2; ++ks)
                        bfr[nf][ks] = *(const bf16x8*)&Bs[buf][bh][r7 * 64 + (((ks * 4 + quad) ^ (r7 & 7)) << 3)];
                }
            }
            bf16x8 af[2][2];                        // this phase's 2 m-frags
            #pragma unroll
            for (int j = 0; j < 2; ++j) {
                int r7 = (2 * q + j) * 16 + l16;
                #pragma unroll
                for (int ks = 0; ks < 2; ++ks)
                    af[j][ks] = *(const bf16x8*)&As[buf][ah][r7 * 64 + (((ks * 4 + quad) ^ (r7 & 7)) << 3)];
            }
            // one half-tile stage per phase (region-safe stream, see header)
            if (q == 0) { if (kt + 1 < 16) stA(buf ^ 1, 0, kt + 1); }
            else if (q == 1) { if (kt + 1 < 16) stA(buf ^ 1, 1, kt + 1); }
            else if (q == 2) { if (kt + 2 < 16) stB(buf, 0, kt + 2); }
            else             { if (kt + 2 < 16) stB(buf, 1, kt + 2); }
            __builtin_amdgcn_s_barrier();
            __builtin_amdgcn_s_setprio(1);
            #pragma unroll
            for (int ks = 0; ks < 2; ++ks)
                #pragma unroll
                for (int j = 0; j < 2; ++j)
                    #pragma unroll
                    for (int nf = 0; nf < 4; ++nf)
                        acc[2 * q + j][nf] = __builtin_amdgcn_mfma_f32_16x16x32_bf16(
                            bfr[nf][ks], af[j][ks], acc[2 * q + j][nf], 0, 0, 0);
            __builtin_amdgcn_s_setprio(0);
            if (q == 3) {                           // T4: counted wait, once per K-tile
                if (kt == 14) asm volatile("s_waitcnt vmcnt(0)" ::: "memory");
                else          asm volatile("s_waitcnt vmcnt(4)" ::: "memory");
            }
            __builtin_amdgcn_s_barrier();
        }
    }

    // epilogue: 256-col tile is qkv-segment-uniform (256 | 1024)
    const int qkv = n0 >> 10;
    const float qs = qkv == 0 ? 0.18033688011112042f : 1.0f;  // log2(e)/sqrt(D)
    #pragma unroll
    for (int nf = 0; nf < 4; ++nf) {
        const int dl = (n0 & 1023) + wn + nf * 16 + (quad << 2);
        const int h = dl >> 6, d0 = dl & 63;        // d0 multiple of 4
        #pragma unroll
        for (int mf = 0; mf < 8; ++mf) {
            const int m = m0 + wm + mf * 16 + l16;
            const int bb = m >> 10, t = m & 1023;
            u16 pk[4];
            #pragma unroll
            for (int r = 0; r < 4; ++r) pk[r] = f2bf(acc[mf][nf][r] * qs);
            if (qkv == 2) {
                // direct V^T write: Vt[bh][d][t]; lanes share d, consecutive t
                const long vb = (long)(bb * SH + h) * SD * ST + t;
                #pragma unroll
                for (int r = 0; r < 4; ++r) Vt[vb + (long)(d0 + r) * ST] = pk[r];
            } else {
                u16* dst = qkv == 0 ? Qb : Kb;
                *(uint2*)&dst[(((long)(bb * SH + h) * ST + t) << 6) + d0] = *(uint2*)pk;
            }
        }
    }
}

// ---- out-projection: C[4096,1024] = Ob * Wpt^T + bias, BM=BN=64, BK=256 ----
// BK=256 staged as 4 x 64-k sub-tiles (contiguous global_load_lds), single
// buffer: 8 barriers total, 32 MFMA/wave per interval. 1024 blocks, 2/CU.
__launch_bounds__(256)
__global__ void k_oproj(const u16* __restrict__ A, const u16* __restrict__ Bt,
                        const float* __restrict__ bias, float* __restrict__ Cout) {
    constexpr int K = 1024, N = 1024;
    __shared__ u16 Als[4][64 * 64];
    __shared__ u16 Bls[4][64 * 64];
    const int tid = threadIdx.x, lane = tid & 63, w = tid >> 6;
    const int quad = lane >> 4, l16 = lane & 15;
    const int sr = lane >> 3, sc = lane & 7;
    const int m0 = (blockIdx.x >> 4) * 64, n0 = (blockIdx.x & 15) * 64;
    const int wm = (w >> 1) * 32, wn = (w & 1) * 32;

    floatx4 acc[2][2] = {};
    for (int kb = 0; kb < 4; ++kb) {
        const int k0 = kb * 256;
        #pragma unroll
        for (int seg = 0; seg < 4; ++seg) {
            #pragma unroll
            for (int i = 0; i < 2; ++i) {
                int rb = (w * 2 + i) * 8;
                gload16(&A[(long)(m0 + rb + sr) * K + k0 + seg * 64 + ((sc ^ sr) << 3)], &Als[seg][rb * 64]);
                gload16(&Bt[(long)(n0 + rb + sr) * K + k0 + seg * 64 + ((sc ^ sr) << 3)], &Bls[seg][rb * 64]);
            }
        }
        __syncthreads();
        #pragma unroll
        for (int seg = 0; seg < 4; ++seg) {
            bf16x8 af[2][2], bfr[2][2];
            #pragma unroll
            for (int sm = 0; sm < 2; ++sm) {
                int row = wm + sm * 16 + l16;
                #pragma unroll
                for (int ks = 0; ks < 2; ++ks)
                    af[sm][ks] = *(const bf16x8*)&Als[seg][row * 64 + (((ks * 4 + quad) ^ (row & 7)) << 3)];
            }
            #pragma unroll
            for (int sn = 0; sn < 2; ++sn) {
                int row = wn + sn * 16 + l16;
                #pragma unroll
                for (int ks = 0; ks < 2; ++ks)
                    bfr[sn][ks] = *(const bf16x8*)&Bls[seg][row * 64 + (((ks * 4 + quad) ^ (row & 7)) << 3)];
            }
            #pragma unroll
            for (int ks = 0; ks < 2; ++ks)
                #pragma unroll
                for (int sm = 0; sm < 2; ++sm)
                    #pragma unroll
                    for (int sn = 0; sn < 2; ++sn)
                        acc[sm][sn] = __builtin_amdgcn_mfma_f32_16x16x32_bf16(bfr[sn][ks], af[sm][ks], acc[sm][sn], 0, 0, 0);
        }
        if (kb < 3) __syncthreads();           // protect LDS before next stage
    }
    #pragma unroll
    for (int sn = 0; sn < 2; ++sn) {
        const int nb = n0 + wn + sn * 16 + (quad << 2);
        const float4 bv = *(const float4*)&bias[nb];
        #pragma unroll
        for (int sm = 0; sm < 2; ++sm) {
            const int m = m0 + wm + sm * 16 + l16;
            float4 o;
            o.x = acc[sm][sn][0] + bv.x;
            o.y = acc[sm][sn][1] + bv.y;
            o.z = acc[sm][sn][2] + bv.z;
            o.w = acc[sm][sn][3] + bv.w;
            *(float4*)&Cout[(long)m * N + nb] = o;
        }
    }
}

// ---- flash attention: 64-row Q tile/block, prefetch double-buffered K/V ----
__launch_bounds__(256)
__global__ void k_attn(const u16* __restrict__ Qg, const u16* __restrict__ Kg,
                       const u16* __restrict__ Vtg, u16* __restrict__ Og) {
    __shared__ u16 Kls[2][64 * 64];   // K tile [s][d], XOR-swizzled chunks
    __shared__ u16 Vls[2][64 * 64];   // Vt tile [d][s], XOR-swizzled chunks
    __shared__ u16 Pls[64 * 64];      // P [t_local][s], per-wave 16-row slices
    const int tid = threadIdx.x, lane = tid & 63, w = tid >> 6;
    const int quad = lane >> 4, l16 = lane & 15;
    const int sr = lane >> 3, sc = lane & 7;
    const int tile = 15 - (blockIdx.x >> 6);       // longest tiles dispatch first
    const int bh = blockIdx.x & 63;
    const int t0 = tile * 64;
    const int b = bh >> 4, h = bh & 15;
    const u16* Qbh = Qg + (long)bh * ST * SD;
    const u16* Kbh = Kg + (long)bh * ST * SD;
    const u16* Vbh = Vtg + (long)bh * SD * ST;     // [d][t]

    bf16x8 qf[2];
    {
        const u16* qrow = Qbh + (t0 + w * 16 + l16) * SD;
        qf[0] = *(const bf16x8*)&qrow[quad * 8];
        qf[1] = *(const bf16x8*)&qrow[32 + quad * 8];
    }
    floatx4 oacc[4] = {};
    float lsum = 0.f;
    const int myt = t0 + w * 16 + l16;             // this lane's global t row
    const int rowP = w * 16 + l16;                 // P row (wave-private)

    auto stage = [&](int buf, int s0) {
        #pragma unroll
        for (int i = 0; i < 2; ++i) {
            int rb = (w * 2 + i) * 8;
            gload16(&Kbh[(s0 + rb + sr) * SD + ((sc ^ sr) << 3)], &Kls[buf][rb * 64]);
            gload16(&Vbh[(rb + sr) * ST + s0 + ((sc ^ sr) << 3)], &Vls[buf][rb * 64]);
        }
    };

    stage(0, 0);
    for (int j = 0; j <= tile; ++j) {
        const int buf = j & 1;
        const int s0 = j * 64;
        __syncthreads();                           // stage(j) visible + compute(j-1) done
        if (j < tile) stage(buf ^ 1, s0 + 64);     // flies during compute

        // S^T = (Q K^T)^T : mfma(K-frag, Q-frag) -> s = quad*4+r, t = l16
        floatx4 sa[4] = {};
        #pragma unroll
        for (int sn = 0; sn < 4; ++sn) {
            int row = sn * 16 + l16;
            #pragma unroll
            for (int ks = 0; ks < 2; ++ks) {
                bf16x8 kf = *(const bf16x8*)&Kls[buf][row * 64 + (((ks * 4 + quad) ^ (row & 7)) << 3)];
                sa[sn] = __builtin_amdgcn_mfma_f32_16x16x32_bf16(kf, qf[ks], sa[sn], 0, 0, 0);
            }
        }
        const bool diag = (j == tile);
        #pragma unroll
        for (int sn = 0; sn < 4; ++sn) {
            const int sl = sn * 16 + (quad << 2);
            u16 pk[4];
            #pragma unroll
            for (int r = 0; r < 4; ++r) {
                float e = __builtin_exp2f(sa[sn][r]);
                if (diag && s0 + sl + r > myt) e = 0.f;
                lsum += e;
                pk[r] = (u16)(__builtin_bit_cast(unsigned int, e) >> 16);  // trunc, e>=0
            }
            *(uint2*)&Pls[rowP * 64 + (((sl >> 3) ^ (rowP & 7)) << 3) + ((quad & 1) << 2)] = *(uint2*)pk;
        }
        // P rows wave-private: lgkmcnt covers RAW, no barrier
        bf16x8 pf[2];
        #pragma unroll
        for (int ks = 0; ks < 2; ++ks)
            pf[ks] = *(const bf16x8*)&Pls[rowP * 64 + (((ks * 4 + quad) ^ (rowP & 7)) << 3)];
        // O^T += (P V)^T : mfma(Vt-frag, P-frag) -> d = quad*4+r, t = l16
        #pragma unroll
        for (int dn = 0; dn < 4; ++dn) {
            int row = dn * 16 + l16;
            #pragma unroll
            for (int ks = 0; ks < 2; ++ks) {
                bf16x8 vf = *(const bf16x8*)&Vls[buf][row * 64 + (((ks * 4 + quad) ^ (row & 7)) << 3)];
                oacc[dn] = __builtin_amdgcn_mfma_f32_16x16x32_bf16(vf, pf[ks], oacc[dn], 0, 0, 0);
            }
        }
    }
    // per-lane row sum: reduce the 4 quads (same t = l16)
    float l = lsum;
    l += __shfl_xor(l, 16);
    l += __shfl_xor(l, 32);
    const float inv = 1.0f / l;
    const long obase = ((long)(b * ST + myt) << 10) + h * SD;
    #pragma unroll
    for (int dn = 0; dn < 4; ++dn) {
        u16 pk[4];
        #pragma unroll
        for (int r = 0; r < 4; ++r) pk[r] = f2bf(oacc[dn][r] * inv);
        *(uint2*)&Og[obase + dn * 16 + (quad << 2)] = *(uint2*)pk;
    }
}

extern "C" void kernel_launch(void* const* d_in, const int* in_sizes, int n_in,
                              void* d_out, int out_size, void* d_ws, size_t ws_size,
                              hipStream_t stream) {
    const float* x  = (const float*)d_in[0];
    const float* Wq = (const float*)d_in[1];
    const float* Wk = (const float*)d_in[2];
    const float* Wv = (const float*)d_in[3];
    const float* Wp = (const float*)d_in[4];
    const float* bp = (const float*)d_in[5];
    float* out = (float*)d_out;

    char* ws = (char*)d_ws;                       // 48 MB used
    u16* xb   = (u16*)(ws);                       // [4096][1024]   8 MB
    u16* Wqkv = (u16*)(ws + (8ll  << 20));        // [3072][1024]   6 MB
    u16* Wpt  = (u16*)(ws + (14ll << 20));        // [1024][1024]   2 MB
    u16* Qb   = (u16*)(ws + (16ll << 20));        // [64][1024][64] 8 MB
    u16* Kb   = (u16*)(ws + (24ll << 20));        // 8 MB
    u16* Vt   = (u16*)(ws + (32ll << 20));        // [64][64][1024] 8 MB
    u16* Ob   = (u16*)(ws + (40ll << 20));        // [4096][1024]   8 MB

    // fused conversions: 4096 (x) + 768 (Wqkv) + 256 (Wp) blocks
    k_prep<<<5120, 256, 0, stream>>>(x, Wq, Wk, Wv, Wp, xb, Wqkv, Wpt);
    // QKV projection: 256x256 8-phase tiles -> 16x12 = 192 blocks, 512 thr
    k_gemm<<<192, 512, 0, stream>>>(xb, Wqkv, Qb, Kb, Vt);
    // attention: 1024 blocks, longest-first (round-5 LDS-staged version)
    k_attn<<<1024, 256, 0, stream>>>(Qb, Kb, Vt, Ob);
    // output projection: 64x64 tiles, BK=256 -> 1024 blocks, 8 barriers
    k_oproj<<<1024, 256, 0, stream>>>(Ob, Wpt, bp, out);
}

// Round 5
// 172.191 us; speedup vs baseline: 1.0113x; 1.0113x over previous
//
#include <hip/hip_runtime.h>
#include <hip/hip_bf16.h>

typedef unsigned short u16;
typedef __bf16 bf16x8 __attribute__((ext_vector_type(8)));
typedef float floatx4 __attribute__((ext_vector_type(4)));

#define SB 4
#define ST 1024
#define SC 1024
#define SH 16
#define SD 64

__device__ __forceinline__ u16 f2bf(float f) {
    unsigned int u = __builtin_bit_cast(unsigned int, f);
    u += 0x7fffu + ((u >> 16) & 1u);   // RNE
    return (u16)(u >> 16);
}

// async 16B/lane global->LDS (m97). LDS dest is wave-uniform base + lane*16.
__device__ __forceinline__ void gload16(const u16* g, u16* l) {
    __builtin_amdgcn_global_load_lds(
        (const __attribute__((address_space(1))) unsigned int*)g,
        (__attribute__((address_space(3))) unsigned int*)l, 16, 0, 0);
}

// ---- fused prep: x->bf16 | Wq/Wk/Wv -> Wqkv[n][c] | Wp -> Wpt[n][k] ----
__global__ void k_prep(const float* __restrict__ x,
                       const float* __restrict__ Wq, const float* __restrict__ Wk,
                       const float* __restrict__ Wv, const float* __restrict__ Wp,
                       u16* __restrict__ xb, u16* __restrict__ Wqkv, u16* __restrict__ Wpt) {
    __shared__ float tile[64 * 65];
    const int id = blockIdx.x, tid = threadIdx.x;
    if (id < 4096) {                               // x: fp32 -> bf16, float4 lanes
        int i = id * 256 + tid;
        float4 v = ((const float4*)x)[i];
        uint2 o;
        o.x = (unsigned)f2bf(v.x) | ((unsigned)f2bf(v.y) << 16);
        o.y = (unsigned)f2bf(v.z) | ((unsigned)f2bf(v.w) << 16);
        ((uint2*)xb)[i] = o;
    } else if (id < 4864) {                        // Wq/Wk/Wv transpose to [n][c]
        const int id1 = id - 4096;
        const int qkv = id1 >> 8, rem = id1 & 255, h = rem >> 4, c0 = (rem & 15) * 64;
        const float* src = qkv == 0 ? Wq : (qkv == 1 ? Wk : Wv);
        #pragma unroll
        for (int i = 0; i < 16; ++i) {
            int idx = tid + i * 256;
            int r = idx >> 6, d = idx & 63;
            tile[r * 65 + d] = src[(h * SC + c0 + r) * SD + d];
        }
        __syncthreads();
        #pragma unroll
        for (int i = 0; i < 16; ++i) {
            int idx = tid + i * 256;
            int d = idx >> 6, cc = idx & 63;
            Wqkv[(qkv * 1024 + h * SD + d) * SC + c0 + cc] = f2bf(tile[cc * 65 + d]);
        }
    } else {                                       // Wp transpose to [n][k]
        const int id2 = id - 4864;
        const int n0 = (id2 & 15) * 64, k0 = (id2 >> 4) * 64;
        #pragma unroll
        for (int i = 0; i < 16; ++i) {
            int idx = tid + i * 256;
            int r = idx >> 6, nn = idx & 63;
            tile[r * 65 + nn] = Wp[(k0 + r) * SC + n0 + nn];
        }
        __syncthreads();
        #pragma unroll
        for (int i = 0; i < 16; ++i) {
            int idx = tid + i * 256;
            int nr = idx >> 6, kk = idx & 63;
            Wpt[(n0 + nr) * (SH * SD) + k0 + kk] = f2bf(tile[kk * 65 + nr]);
        }
    }
}

// ---- QKV GEMM: C = A[4096,1024] * Bt[3072,1024]^T, bf16 ----
// BM=128, BN=96, BK=64, dbuf prefetch. Grid 32x32 = 1024 blocks @ 56KB
// LDS -> 2 blocks/CU -> exactly 2 full waves of blocks (best measured
// gemm config, round 3; 2-phase structure ceiling ~600 TF — pinned).
// Swapped-operand MFMA -> D^T per-lane: m = l16, n = quad*4+r.
// Q (pre-scaled by log2e/8) / K -> [bh][t][d]; V -> Vt[bh][d][t].
__launch_bounds__(256)
__global__ void k_gemm(const u16* __restrict__ A, const u16* __restrict__ Bt,
                       u16* __restrict__ Qb, u16* __restrict__ Kb, u16* __restrict__ Vt) {
    constexpr int K = 1024, BM = 128, BN = 96, SM = 4, SN = 3;
    __shared__ u16 Als[2][BM * 64];
    __shared__ u16 Bls[2][BN * 64];
    const int tid = threadIdx.x, lane = tid & 63, w = tid >> 6;
    const int quad = lane >> 4, l16 = lane & 15;
    const int sr = lane >> 3, sc = lane & 7;
    const int m0 = (blockIdx.x >> 5) * BM, n0 = (blockIdx.x & 31) * BN;
    const int wm = (w >> 1) * 64, wn = (w & 1) * 48;

    auto stage = [&](int buf, int k0) {
        #pragma unroll
        for (int i = 0; i < 4; ++i) {
            int rb = (w * 4 + i) * 8;
            gload16(&A[(long)(m0 + rb + sr) * K + k0 + ((sc ^ sr) << 3)], &Als[buf][rb * 64]);
        }
        #pragma unroll
        for (int i = 0; i < 3; ++i) {
            int rb = (w * 3 + i) * 8;
            gload16(&Bt[(long)(n0 + rb + sr) * K + k0 + ((sc ^ sr) << 3)], &Bls[buf][rb * 64]);
        }
    };

    floatx4 acc[SM][SN] = {};
    stage(0, 0);
    for (int it = 0; it < 16; ++it) {
        const int buf = it & 1;
        __syncthreads();                       // stage(it) visible + compute(it-1) done
        if (it < 15) stage(buf ^ 1, (it + 1) * 64);   // flies during compute
        bf16x8 af[SM][2], bfr[SN][2];
        #pragma unroll
        for (int sm = 0; sm < SM; ++sm) {
            int row = wm + sm * 16 + l16;
            #pragma unroll
            for (int ks = 0; ks < 2; ++ks)
                af[sm][ks] = *(const bf16x8*)&Als[buf][row * 64 + (((ks * 4 + quad) ^ (row & 7)) << 3)];
        }
        #pragma unroll
        for (int sn = 0; sn < SN; ++sn) {
            int row = wn + sn * 16 + l16;
            #pragma unroll
            for (int ks = 0; ks < 2; ++ks)
                bfr[sn][ks] = *(const bf16x8*)&Bls[buf][row * 64 + (((ks * 4 + quad) ^ (row & 7)) << 3)];
        }
        #pragma unroll
        for (int ks = 0; ks < 2; ++ks)
            #pragma unroll
            for (int sm = 0; sm < SM; ++sm)
                #pragma unroll
                for (int sn = 0; sn < SN; ++sn)
                    acc[sm][sn] = __builtin_amdgcn_mfma_f32_16x16x32_bf16(bfr[sn][ks], af[sm][ks], acc[sm][sn], 0, 0, 0);
    }
    // epilogue: per 16-col subtile (segment-uniform since 16 | 1024)
    #pragma unroll
    for (int sn = 0; sn < SN; ++sn) {
        const int c0 = n0 + wn + sn * 16;          // multiple of 16
        const int qkv = c0 >> 10;
        const float qs = qkv == 0 ? 0.18033688011112042f : 1.0f;  // log2(e)/sqrt(D)
        const int cs = (c0 & 1023) + (quad << 2);  // col within segment
        const int h = cs >> 6, d0 = cs & 63;       // d0 multiple of 4
        #pragma unroll
        for (int sm = 0; sm < SM; ++sm) {
            const int m = m0 + wm + sm * 16 + l16;
            const int bb = m >> 10, t = m & 1023;
            u16 pk[4];
            #pragma unroll
            for (int r = 0; r < 4; ++r) pk[r] = f2bf(acc[sm][sn][r] * qs);
            if (qkv == 2) {
                // direct V^T write: Vt[bh][d][t]; lanes share d, consecutive t
                const long vb = (long)(bb * SH + h) * SD * ST + t;
                #pragma unroll
                for (int r = 0; r < 4; ++r) Vt[vb + (long)(d0 + r) * ST] = pk[r];
            } else {
                u16* dst = qkv == 0 ? Qb : Kb;
                *(uint2*)&dst[(((long)(bb * SH + h) * ST + t) << 6) + d0] = *(uint2*)pk;
            }
        }
    }
}

// ---- out-projection: C[4096,1024] = Ob * Wpt^T + bias, BM=128 BN=64 ----
// Proven dbuf-prefetch skeleton (round-0 gemm geometry). Grid 32x16 = 512
// blocks @ 48KB LDS -> 3 blocks/CU capacity -> all 512 resident, no tail.
__launch_bounds__(256)
__global__ void k_oproj(const u16* __restrict__ A, const u16* __restrict__ Bt,
                        const float* __restrict__ bias, float* __restrict__ Cout) {
    constexpr int K = 1024, N = 1024, BM = 128, BN = 64, SM = 4, SN = 2;
    __shared__ u16 Als[2][BM * 64];
    __shared__ u16 Bls[2][BN * 64];
    const int tid = threadIdx.x, lane = tid & 63, w = tid >> 6;
    const int quad = lane >> 4, l16 = lane & 15;
    const int sr = lane >> 3, sc = lane & 7;
    const int m0 = (blockIdx.x >> 4) * BM, n0 = (blockIdx.x & 15) * BN;
    const int wm = (w >> 1) * 64, wn = (w & 1) * 32;

    auto stage = [&](int buf, int k0) {
        #pragma unroll
        for (int i = 0; i < 4; ++i) {
            int rb = (w * 4 + i) * 8;
            gload16(&A[(long)(m0 + rb + sr) * K + k0 + ((sc ^ sr) << 3)], &Als[buf][rb * 64]);
        }
        #pragma unroll
        for (int i = 0; i < 2; ++i) {
            int rb = (w * 2 + i) * 8;
            gload16(&Bt[(long)(n0 + rb + sr) * K + k0 + ((sc ^ sr) << 3)], &Bls[buf][rb * 64]);
        }
    };

    floatx4 acc[SM][SN] = {};
    stage(0, 0);
    for (int it = 0; it < 16; ++it) {
        const int buf = it & 1;
        __syncthreads();                       // stage(it) visible + compute(it-1) done
        if (it < 15) stage(buf ^ 1, (it + 1) * 64);   // flies during compute
        bf16x8 af[SM][2], bfr[SN][2];
        #pragma unroll
        for (int sm = 0; sm < SM; ++sm) {
            int row = wm + sm * 16 + l16;
            #pragma unroll
            for (int ks = 0; ks < 2; ++ks)
                af[sm][ks] = *(const bf16x8*)&Als[buf][row * 64 + (((ks * 4 + quad) ^ (row & 7)) << 3)];
        }
        #pragma unroll
        for (int sn = 0; sn < SN; ++sn) {
            int row = wn + sn * 16 + l16;
            #pragma unroll
            for (int ks = 0; ks < 2; ++ks)
                bfr[sn][ks] = *(const bf16x8*)&Bls[buf][row * 64 + (((ks * 4 + quad) ^ (row & 7)) << 3)];
        }
        #pragma unroll
        for (int ks = 0; ks < 2; ++ks)
            #pragma unroll
            for (int sm = 0; sm < SM; ++sm)
                #pragma unroll
                for (int sn = 0; sn < SN; ++sn)
                    acc[sm][sn] = __builtin_amdgcn_mfma_f32_16x16x32_bf16(bfr[sn][ks], af[sm][ks], acc[sm][sn], 0, 0, 0);
    }
    #pragma unroll
    for (int sn = 0; sn < SN; ++sn) {
        const int nb = n0 + wn + sn * 16 + (quad << 2);
        const float4 bv = *(const float4*)&bias[nb];
        #pragma unroll
        for (int sm = 0; sm < SM; ++sm) {
            const int m = m0 + wm + sm * 16 + l16;
            float4 o;
            o.x = acc[sm][sn][0] + bv.x;
            o.y = acc[sm][sn][1] + bv.y;
            o.z = acc[sm][sn][2] + bv.z;
            o.w = acc[sm][sn][3] + bv.w;
            *(float4*)&Cout[(long)m * N + nb] = o;
        }
    }
}

// ---- flash attention: 128-row Q tile/block (QBLK=128) ----
// Each staged K/V tile now feeds BOTH Q-halves: every kf/vf ds_read is
// reused by 2 MFMAs, and global staging + barriers per MFMA are HALVED
// vs the 64-row version (34 -> 18 intervals/CU).
// Causal mask applied unconditionally: e = (s > myt) ? 0 : exp2(s*scale)
// — also correct for the fully-masked half-0 corner tile (~6% waste).
// qt mapping pairs long+short blocks per CU: g<4 ? 7-g : g-4.
__launch_bounds__(256)
__global__ void k_attn(const u16* __restrict__ Qg, const u16* __restrict__ Kg,
                       const u16* __restrict__ Vtg, u16* __restrict__ Og) {
    __shared__ u16 Kls[2][64 * 64];   // K tile [s][d], XOR-swizzled chunks
    __shared__ u16 Vls[2][64 * 64];   // Vt tile [d][s], XOR-swizzled chunks
    __shared__ u16 Pls[128 * 64];     // P [t_local][s], per-wave 16-row slices x 2 halves
    const int tid = threadIdx.x, lane = tid & 63, w = tid >> 6;
    const int quad = lane >> 4, l16 = lane & 15;
    const int sr = lane >> 3, sc = lane & 7;
    const int g = blockIdx.x >> 6;
    const int qt = (g < 4) ? (7 - g) : (g - 4);    // pair 16+2,14+4,12+6,10+8 intervals/CU
    const int bh = blockIdx.x & 63;
    const int t0 = qt * 128;
    const int b = bh >> 4, h = bh & 15;
    const u16* Qbh = Qg + (long)bh * ST * SD;
    const u16* Kbh = Kg + (long)bh * ST * SD;
    const u16* Vbh = Vtg + (long)bh * SD * ST;     // [d][t]

    bf16x8 qf[2][2];
    #pragma unroll
    for (int half = 0; half < 2; ++half) {
        const u16* qrow = Qbh + (t0 + half * 64 + w * 16 + l16) * SD;
        qf[half][0] = *(const bf16x8*)&qrow[quad * 8];
        qf[half][1] = *(const bf16x8*)&qrow[32 + quad * 8];
    }
    floatx4 oacc[2][4] = {};
    float lsum[2] = {0.f, 0.f};
    const int rowP = w * 16 + l16;                 // P row within a half (wave-private)

    auto stage = [&](int buf, int s0) {
        #pragma unroll
        for (int i = 0; i < 2; ++i) {
            int rb = (w * 2 + i) * 8;
            gload16(&Kbh[(s0 + rb + sr) * SD + ((sc ^ sr) << 3)], &Kls[buf][rb * 64]);
            gload16(&Vbh[(rb + sr) * ST + s0 + ((sc ^ sr) << 3)], &Vls[buf][rb * 64]);
        }
    };

    const int jmax = 2 * qt + 1;
    stage(0, 0);
    for (int j = 0; j <= jmax; ++j) {
        const int buf = j & 1;
        const int s0 = j * 64;
        __syncthreads();                           // stage(j) visible + compute(j-1) done
        if (j < jmax) stage(buf ^ 1, s0 + 64);     // flies during compute

        // S^T = (Q K^T)^T for both halves, sharing each kf read
        floatx4 sa[2][4] = {};
        #pragma unroll
        for (int sn = 0; sn < 4; ++sn) {
            int row = sn * 16 + l16;
            #pragma unroll
            for (int ks = 0; ks < 2; ++ks) {
                bf16x8 kf = *(const bf16x8*)&Kls[buf][row * 64 + (((ks * 4 + quad) ^ (row & 7)) << 3)];
                sa[0][sn] = __builtin_amdgcn_mfma_f32_16x16x32_bf16(kf, qf[0][ks], sa[0][sn], 0, 0, 0);
                sa[1][sn] = __builtin_amdgcn_mfma_f32_16x16x32_bf16(kf, qf[1][ks], sa[1][sn], 0, 0, 0);
            }
        }
        // softmax numerators + P store, both halves
        #pragma unroll
        for (int half = 0; half < 2; ++half) {
            const int myt_h = t0 + half * 64 + w * 16 + l16;
            const int rp = half * 64 + rowP;
            #pragma unroll
            for (int sn = 0; sn < 4; ++sn) {
                const int sl = sn * 16 + (quad << 2);
                u16 pk[4];
                #pragma unroll
                for (int r = 0; r < 4; ++r) {
                    float e = __builtin_exp2f(sa[half][sn][r]);
                    if (s0 + sl + r > myt_h) e = 0.f;          // causal (always correct)
                    lsum[half] += e;
                    pk[r] = (u16)(__builtin_bit_cast(unsigned int, e) >> 16);  // trunc, e>=0
                }
                *(uint2*)&Pls[rp * 64 + (((sl >> 3) ^ (rp & 7)) << 3) + ((quad & 1) << 2)] = *(uint2*)pk;
            }
        }
        // P rows wave-private: lgkmcnt covers RAW, no barrier
        bf16x8 pf[2][2];
        #pragma unroll
        for (int half = 0; half < 2; ++half) {
            const int rp = half * 64 + rowP;
            #pragma unroll
            for (int ks = 0; ks < 2; ++ks)
                pf[half][ks] = *(const bf16x8*)&Pls[rp * 64 + (((ks * 4 + quad) ^ (rp & 7)) << 3)];
        }
        // O^T += (P V)^T for both halves, sharing each vf read
        #pragma unroll
        for (int dn = 0; dn < 4; ++dn) {
            int row = dn * 16 + l16;
            #pragma unroll
            for (int ks = 0; ks < 2; ++ks) {
                bf16x8 vf = *(const bf16x8*)&Vls[buf][row * 64 + (((ks * 4 + quad) ^ (row & 7)) << 3)];
                oacc[0][dn] = __builtin_amdgcn_mfma_f32_16x16x32_bf16(vf, pf[0][ks], oacc[0][dn], 0, 0, 0);
                oacc[1][dn] = __builtin_amdgcn_mfma_f32_16x16x32_bf16(vf, pf[1][ks], oacc[1][dn], 0, 0, 0);
            }
        }
    }
    // per-lane row sums: reduce the 4 quads (same t = l16), both halves
    #pragma unroll
    for (int half = 0; half < 2; ++half) {
        float l = lsum[half];
        l += __shfl_xor(l, 16);
        l += __shfl_xor(l, 32);
        const float inv = 1.0f / l;
        const int myt_h = t0 + half * 64 + w * 16 + l16;
        const long obase = ((long)(b * ST + myt_h) << 10) + h * SD;
        #pragma unroll
        for (int dn = 0; dn < 4; ++dn) {
            u16 pk[4];
            #pragma unroll
            for (int r = 0; r < 4; ++r) pk[r] = f2bf(oacc[half][dn][r] * inv);
            *(uint2*)&Og[obase + dn * 16 + (quad << 2)] = *(uint2*)pk;
        }
    }
}

extern "C" void kernel_launch(void* const* d_in, const int* in_sizes, int n_in,
                              void* d_out, int out_size, void* d_ws, size_t ws_size,
                              hipStream_t stream) {
    const float* x  = (const float*)d_in[0];
    const float* Wq = (const float*)d_in[1];
    const float* Wk = (const float*)d_in[2];
    const float* Wv = (const float*)d_in[3];
    const float* Wp = (const float*)d_in[4];
    const float* bp = (const float*)d_in[5];
    float* out = (float*)d_out;

    char* ws = (char*)d_ws;                       // 48 MB used
    u16* xb   = (u16*)(ws);                       // [4096][1024]   8 MB
    u16* Wqkv = (u16*)(ws + (8ll  << 20));        // [3072][1024]   6 MB
    u16* Wpt  = (u16*)(ws + (14ll << 20));        // [1024][1024]   2 MB
    u16* Qb   = (u16*)(ws + (16ll << 20));        // [64][1024][64] 8 MB
    u16* Kb   = (u16*)(ws + (24ll << 20));        // 8 MB
    u16* Vt   = (u16*)(ws + (32ll << 20));        // [64][64][1024] 8 MB
    u16* Ob   = (u16*)(ws + (40ll << 20));        // [4096][1024]   8 MB

    // fused conversions: 4096 (x) + 768 (Wqkv) + 256 (Wp) blocks
    k_prep<<<5120, 256, 0, stream>>>(x, Wq, Wk, Wv, Wp, xb, Wqkv, Wpt);
    // QKV projection: M=4096 N=3072 K=1024, 128x96 tiles -> 1024 blocks (2 full waves)
    k_gemm<<<1024, 256, 0, stream>>>(xb, Wqkv, Qb, Kb, Vt);
    // attention: QBLK=128 -> 8 qtiles x 64 bh = 512 blocks, paired long+short
    k_attn<<<512, 256, 0, stream>>>(Qb, Kb, Vt, Ob);
    // output projection: 128x64 tiles -> 512 blocks, dbuf prefetch
    k_oproj<<<512, 256, 0, stream>>>(Ob, Wpt, bp, out);
}

// Round 6
// 163.414 us; speedup vs baseline: 1.0656x; 1.0537x over previous
//
#include <hip/hip_runtime.h>
#include <hip/hip_bf16.h>

typedef unsigned short u16;
typedef __bf16 bf16x8 __attribute__((ext_vector_type(8)));
typedef float floatx4 __attribute__((ext_vector_type(4)));

#define SB 4
#define ST 1024
#define SC 1024
#define SH 16
#define SD 64

__device__ __forceinline__ u16 f2bf(float f) {
    unsigned int u = __builtin_bit_cast(unsigned int, f);
    u += 0x7fffu + ((u >> 16) & 1u);   // RNE
    return (u16)(u >> 16);
}

// async 16B/lane global->LDS (m97). LDS dest is wave-uniform base + lane*16.
__device__ __forceinline__ void gload16(const u16* g, u16* l) {
    __builtin_amdgcn_global_load_lds(
        (const __attribute__((address_space(1))) unsigned int*)g,
        (__attribute__((address_space(3))) unsigned int*)l, 16, 0, 0);
}

// ---- fused prep: x->bf16 | Wq/Wk/Wv -> Wqkv[n][c] | Wp -> Wpt[n][k] ----
__global__ void k_prep(const float* __restrict__ x,
                       const float* __restrict__ Wq, const float* __restrict__ Wk,
                       const float* __restrict__ Wv, const float* __restrict__ Wp,
                       u16* __restrict__ xb, u16* __restrict__ Wqkv, u16* __restrict__ Wpt) {
    __shared__ float tile[64 * 65];
    const int id = blockIdx.x, tid = threadIdx.x;
    if (id < 4096) {                               // x: fp32 -> bf16, float4 lanes
        int i = id * 256 + tid;
        float4 v = ((const float4*)x)[i];
        uint2 o;
        o.x = (unsigned)f2bf(v.x) | ((unsigned)f2bf(v.y) << 16);
        o.y = (unsigned)f2bf(v.z) | ((unsigned)f2bf(v.w) << 16);
        ((uint2*)xb)[i] = o;
    } else if (id < 4864) {                        // Wq/Wk/Wv transpose to [n][c]
        const int id1 = id - 4096;
        const int qkv = id1 >> 8, rem = id1 & 255, h = rem >> 4, c0 = (rem & 15) * 64;
        const float* src = qkv == 0 ? Wq : (qkv == 1 ? Wk : Wv);
        #pragma unroll
        for (int i = 0; i < 16; ++i) {
            int idx = tid + i * 256;
            int r = idx >> 6, d = idx & 63;
            tile[r * 65 + d] = src[(h * SC + c0 + r) * SD + d];
        }
        __syncthreads();
        #pragma unroll
        for (int i = 0; i < 16; ++i) {
            int idx = tid + i * 256;
            int d = idx >> 6, cc = idx & 63;
            Wqkv[(qkv * 1024 + h * SD + d) * SC + c0 + cc] = f2bf(tile[cc * 65 + d]);
        }
    } else {                                       // Wp transpose to [n][k]
        const int id2 = id - 4864;
        const int n0 = (id2 & 15) * 64, k0 = (id2 >> 4) * 64;
        #pragma unroll
        for (int i = 0; i < 16; ++i) {
            int idx = tid + i * 256;
            int r = idx >> 6, nn = idx & 63;
            tile[r * 65 + nn] = Wp[(k0 + r) * SC + n0 + nn];
        }
        __syncthreads();
        #pragma unroll
        for (int i = 0; i < 16; ++i) {
            int idx = tid + i * 256;
            int nr = idx >> 6, kk = idx & 63;
            Wpt[(n0 + nr) * (SH * SD) + k0 + kk] = f2bf(tile[kk * 65 + nr]);
        }
    }
}

// ---- QKV GEMM: C = A[M,K] * Bt[N,K]^T, bf16, BM=128, BN=64, BK=64 ----
// (R0-exact: best-measured total config, 42.9 us)
// Single-barrier prefetch double-buffer. Swapped-operand MFMA -> D^T per-lane:
// m = l16, n = quad*4+r (packed stores).
// Q (pre-scaled by log2e/8) / K -> [bh][t][d]; V -> Vt[bh][d][t].
__launch_bounds__(256)
__global__ void k_gemm(const u16* __restrict__ A, const u16* __restrict__ Bt,
                       int M, int N, int K,
                       u16* __restrict__ Qb, u16* __restrict__ Kb, u16* __restrict__ Vt) {
    constexpr int BM = 128, BN = 64, SM = 4, SN = 2;
    __shared__ u16 Als[2][BM * 64];
    __shared__ u16 Bls[2][BN * 64];
    const int tid = threadIdx.x, lane = tid & 63, w = tid >> 6;
    const int quad = lane >> 4, l16 = lane & 15;
    const int sr = lane >> 3, sc = lane & 7;
    const int nt = N / BN;
    const int m0 = (blockIdx.x / nt) * BM, n0 = (blockIdx.x % nt) * BN;
    const int wm = (w >> 1) * 64, wn = (w & 1) * 32;

    auto stage = [&](int buf, int k0) {
        #pragma unroll
        for (int i = 0; i < 4; ++i) {
            int rb = (w * 4 + i) * 8;
            gload16(&A[(long)(m0 + rb + sr) * K + k0 + ((sc ^ sr) << 3)], &Als[buf][rb * 64]);
        }
        #pragma unroll
        for (int i = 0; i < 2; ++i) {
            int rb = (w * 2 + i) * 8;
            gload16(&Bt[(long)(n0 + rb + sr) * K + k0 + ((sc ^ sr) << 3)], &Bls[buf][rb * 64]);
        }
    };

    floatx4 acc[SM][SN] = {};
    const int niter = K / 64;
    stage(0, 0);
    for (int it = 0; it < niter; ++it) {
        const int buf = it & 1;
        __syncthreads();                       // stage(it) visible + compute(it-1) done
        if (it + 1 < niter) stage(buf ^ 1, (it + 1) * 64);   // flies during compute
        bf16x8 af[SM][2], bfr[SN][2];
        #pragma unroll
        for (int sm = 0; sm < SM; ++sm) {
            int row = wm + sm * 16 + l16;
            #pragma unroll
            for (int ks = 0; ks < 2; ++ks)
                af[sm][ks] = *(const bf16x8*)&Als[buf][row * 64 + (((ks * 4 + quad) ^ (row & 7)) << 3)];
        }
        #pragma unroll
        for (int sn = 0; sn < SN; ++sn) {
            int row = wn + sn * 16 + l16;
            #pragma unroll
            for (int ks = 0; ks < 2; ++ks)
                bfr[sn][ks] = *(const bf16x8*)&Bls[buf][row * 64 + (((ks * 4 + quad) ^ (row & 7)) << 3)];
        }
        #pragma unroll
        for (int ks = 0; ks < 2; ++ks)
            #pragma unroll
            for (int sm = 0; sm < SM; ++sm)
                #pragma unroll
                for (int sn = 0; sn < SN; ++sn)
                    acc[sm][sn] = __builtin_amdgcn_mfma_f32_16x16x32_bf16(bfr[sn][ks], af[sm][ks], acc[sm][sn], 0, 0, 0);
    }
    const int qkv = n0 >> 10, h = (n0 & 1023) >> 6;     // uniform per block
    const float qs = qkv == 0 ? 0.18033688011112042f : 1.0f;  // log2(e)/sqrt(D)
    #pragma unroll
    for (int sm = 0; sm < SM; ++sm) {
        const int m = m0 + wm + sm * 16 + l16;
        const int bb = m >> 10, t = m & 1023;
        #pragma unroll
        for (int sn = 0; sn < SN; ++sn) {
            const int d0 = wn + sn * 16 + (quad << 2);
            u16 pk[4];
            #pragma unroll
            for (int r = 0; r < 4; ++r) pk[r] = f2bf(acc[sm][sn][r] * qs);
            if (qkv == 2) {
                // direct V^T write: Vt[bh][d][t]; lanes share d, consecutive t
                const long vb = (long)(bb * SH + h) * SD * ST + t;
                #pragma unroll
                for (int r = 0; r < 4; ++r) Vt[vb + (long)(d0 + r) * ST] = pk[r];
            } else {
                u16* dst = qkv == 0 ? Qb : Kb;
                *(uint2*)&dst[(((long)(bb * SH + h) * ST + t) << 6) + d0] = *(uint2*)pk;
            }
        }
    }
}

// ---- out-projection: C[4096,1024] = Ob * Wpt^T + bias, BM=128 BN=64 ----
// THE ONE CHANGE vs R0: same proven dbuf-prefetch skeleton as k_gemm
// (which does 3x the FLOPs in 42.9 us -> ~14 us expected here).
// Grid 32x16 = 512 blocks @ 48KB LDS -> all 512 co-resident (2/CU), no tail.
__launch_bounds__(256)
__global__ void k_oproj(const u16* __restrict__ A, const u16* __restrict__ Bt,
                        const float* __restrict__ bias, float* __restrict__ Cout) {
    constexpr int K = 1024, N = 1024, BM = 128, BN = 64, SM = 4, SN = 2;
    __shared__ u16 Als[2][BM * 64];
    __shared__ u16 Bls[2][BN * 64];
    const int tid = threadIdx.x, lane = tid & 63, w = tid >> 6;
    const int quad = lane >> 4, l16 = lane & 15;
    const int sr = lane >> 3, sc = lane & 7;
    const int m0 = (blockIdx.x >> 4) * BM, n0 = (blockIdx.x & 15) * BN;
    const int wm = (w >> 1) * 64, wn = (w & 1) * 32;

    auto stage = [&](int buf, int k0) {
        #pragma unroll
        for (int i = 0; i < 4; ++i) {
            int rb = (w * 4 + i) * 8;
            gload16(&A[(long)(m0 + rb + sr) * K + k0 + ((sc ^ sr) << 3)], &Als[buf][rb * 64]);
        }
        #pragma unroll
        for (int i = 0; i < 2; ++i) {
            int rb = (w * 2 + i) * 8;
            gload16(&Bt[(long)(n0 + rb + sr) * K + k0 + ((sc ^ sr) << 3)], &Bls[buf][rb * 64]);
        }
    };

    floatx4 acc[SM][SN] = {};
    stage(0, 0);
    for (int it = 0; it < 16; ++it) {
        const int buf = it & 1;
        __syncthreads();                       // stage(it) visible + compute(it-1) done
        if (it < 15) stage(buf ^ 1, (it + 1) * 64);   // flies during compute
        bf16x8 af[SM][2], bfr[SN][2];
        #pragma unroll
        for (int sm = 0; sm < SM; ++sm) {
            int row = wm + sm * 16 + l16;
            #pragma unroll
            for (int ks = 0; ks < 2; ++ks)
                af[sm][ks] = *(const bf16x8*)&Als[buf][row * 64 + (((ks * 4 + quad) ^ (row & 7)) << 3)];
        }
        #pragma unroll
        for (int sn = 0; sn < SN; ++sn) {
            int row = wn + sn * 16 + l16;
            #pragma unroll
            for (int ks = 0; ks < 2; ++ks)
                bfr[sn][ks] = *(const bf16x8*)&Bls[buf][row * 64 + (((ks * 4 + quad) ^ (row & 7)) << 3)];
        }
        #pragma unroll
        for (int ks = 0; ks < 2; ++ks)
            #pragma unroll
            for (int sm = 0; sm < SM; ++sm)
                #pragma unroll
                for (int sn = 0; sn < SN; ++sn)
                    acc[sm][sn] = __builtin_amdgcn_mfma_f32_16x16x32_bf16(bfr[sn][ks], af[sm][ks], acc[sm][sn], 0, 0, 0);
    }
    #pragma unroll
    for (int sn = 0; sn < SN; ++sn) {
        const int nb = n0 + wn + sn * 16 + (quad << 2);
        const float4 bv = *(const float4*)&bias[nb];
        #pragma unroll
        for (int sm = 0; sm < SM; ++sm) {
            const int m = m0 + wm + sm * 16 + l16;
            float4 o;
            o.x = acc[sm][sn][0] + bv.x;
            o.y = acc[sm][sn][1] + bv.y;
            o.z = acc[sm][sn][2] + bv.z;
            o.w = acc[sm][sn][3] + bv.w;
            *(float4*)&Cout[(long)m * N + nb] = o;
        }
    }
}

// ---- flash attention: 64-row Q tile/block, prefetch double-buffered K/V ----
// (R0-exact round-5-prior version — LDS cooperative staging)
__launch_bounds__(256)
__global__ void k_attn(const u16* __restrict__ Qg, const u16* __restrict__ Kg,
                       const u16* __restrict__ Vtg, u16* __restrict__ Og) {
    __shared__ u16 Kls[2][64 * 64];   // K tile [s][d], XOR-swizzled chunks
    __shared__ u16 Vls[2][64 * 64];   // Vt tile [d][s], XOR-swizzled chunks
    __shared__ u16 Pls[64 * 64];      // P [t_local][s], per-wave 16-row slices
    const int tid = threadIdx.x, lane = tid & 63, w = tid >> 6;
    const int quad = lane >> 4, l16 = lane & 15;
    const int sr = lane >> 3, sc = lane & 7;
    const int tile = 15 - (blockIdx.x >> 6);       // longest tiles dispatch first
    const int bh = blockIdx.x & 63;
    const int t0 = tile * 64;
    const int b = bh >> 4, h = bh & 15;
    const u16* Qbh = Qg + (long)bh * ST * SD;
    const u16* Kbh = Kg + (long)bh * ST * SD;
    const u16* Vbh = Vtg + (long)bh * SD * ST;     // [d][t]

    bf16x8 qf[2];
    {
        const u16* qrow = Qbh + (t0 + w * 16 + l16) * SD;
        qf[0] = *(const bf16x8*)&qrow[quad * 8];
        qf[1] = *(const bf16x8*)&qrow[32 + quad * 8];
    }
    floatx4 oacc[4] = {};
    float lsum = 0.f;
    const int myt = t0 + w * 16 + l16;             // this lane's global t row
    const int rowP = w * 16 + l16;                 // P row (wave-private)

    auto stage = [&](int buf, int s0) {
        #pragma unroll
        for (int i = 0; i < 2; ++i) {
            int rb = (w * 2 + i) * 8;
            gload16(&Kbh[(s0 + rb + sr) * SD + ((sc ^ sr) << 3)], &Kls[buf][rb * 64]);
            gload16(&Vbh[(rb + sr) * ST + s0 + ((sc ^ sr) << 3)], &Vls[buf][rb * 64]);
        }
    };

    stage(0, 0);
    for (int j = 0; j <= tile; ++j) {
        const int buf = j & 1;
        const int s0 = j * 64;
        __syncthreads();                           // stage(j) visible + compute(j-1) done
        if (j < tile) stage(buf ^ 1, s0 + 64);     // flies during compute

        // S^T = (Q K^T)^T : mfma(K-frag, Q-frag) -> s = quad*4+r, t = l16
        floatx4 sa[4] = {};
        #pragma unroll
        for (int sn = 0; sn < 4; ++sn) {
            int row = sn * 16 + l16;
            #pragma unroll
            for (int ks = 0; ks < 2; ++ks) {
                bf16x8 kf = *(const bf16x8*)&Kls[buf][row * 64 + (((ks * 4 + quad) ^ (row & 7)) << 3)];
                sa[sn] = __builtin_amdgcn_mfma_f32_16x16x32_bf16(kf, qf[ks], sa[sn], 0, 0, 0);
            }
        }
        const bool diag = (j == tile);
        #pragma unroll
        for (int sn = 0; sn < 4; ++sn) {
            const int sl = sn * 16 + (quad << 2);
            u16 pk[4];
            #pragma unroll
            for (int r = 0; r < 4; ++r) {
                float e = __builtin_exp2f(sa[sn][r]);
                if (diag && s0 + sl + r > myt) e = 0.f;
                lsum += e;
                pk[r] = (u16)(__builtin_bit_cast(unsigned int, e) >> 16);  // trunc, e>=0
            }
            *(uint2*)&Pls[rowP * 64 + (((sl >> 3) ^ (rowP & 7)) << 3) + ((quad & 1) << 2)] = *(uint2*)pk;
        }
        // P rows wave-private: lgkmcnt covers RAW, no barrier
        bf16x8 pf[2];
        #pragma unroll
        for (int ks = 0; ks < 2; ++ks)
            pf[ks] = *(const bf16x8*)&Pls[rowP * 64 + (((ks * 4 + quad) ^ (rowP & 7)) << 3)];
        // O^T += (P V)^T : mfma(Vt-frag, P-frag) -> d = quad*4+r, t = l16
        #pragma unroll
        for (int dn = 0; dn < 4; ++dn) {
            int row = dn * 16 + l16;
            #pragma unroll
            for (int ks = 0; ks < 2; ++ks) {
                bf16x8 vf = *(const bf16x8*)&Vls[buf][row * 64 + (((ks * 4 + quad) ^ (row & 7)) << 3)];
                oacc[dn] = __builtin_amdgcn_mfma_f32_16x16x32_bf16(vf, pf[ks], oacc[dn], 0, 0, 0);
            }
        }
    }
    // per-lane row sum: reduce the 4 quads (same t = l16)
    float l = lsum;
    l += __shfl_xor(l, 16);
    l += __shfl_xor(l, 32);
    const float inv = 1.0f / l;
    const long obase = ((long)(b * ST + myt) << 10) + h * SD;
    #pragma unroll
    for (int dn = 0; dn < 4; ++dn) {
        u16 pk[4];
        #pragma unroll
        for (int r = 0; r < 4; ++r) pk[r] = f2bf(oacc[dn][r] * inv);
        *(uint2*)&Og[obase + dn * 16 + (quad << 2)] = *(uint2*)pk;
    }
}

extern "C" void kernel_launch(void* const* d_in, const int* in_sizes, int n_in,
                              void* d_out, int out_size, void* d_ws, size_t ws_size,
                              hipStream_t stream) {
    const float* x  = (const float*)d_in[0];
    const float* Wq = (const float*)d_in[1];
    const float* Wk = (const float*)d_in[2];
    const float* Wv = (const float*)d_in[3];
    const float* Wp = (const float*)d_in[4];
    const float* bp = (const float*)d_in[5];
    float* out = (float*)d_out;

    char* ws = (char*)d_ws;                       // 48 MB used
    u16* xb   = (u16*)(ws);                       // [4096][1024]   8 MB
    u16* Wqkv = (u16*)(ws + (8ll  << 20));        // [3072][1024]   6 MB
    u16* Wpt  = (u16*)(ws + (14ll << 20));        // [1024][1024]   2 MB
    u16* Qb   = (u16*)(ws + (16ll << 20));        // [64][1024][64] 8 MB
    u16* Kb   = (u16*)(ws + (24ll << 20));        // 8 MB
    u16* Vt   = (u16*)(ws + (32ll << 20));        // [64][64][1024] 8 MB
    u16* Ob   = (u16*)(ws + (40ll << 20));        // [4096][1024]   8 MB

    // fused conversions: 4096 (x) + 768 (Wqkv) + 256 (Wp) blocks
    k_prep<<<5120, 256, 0, stream>>>(x, Wq, Wk, Wv, Wp, xb, Wqkv, Wpt);
    // QKV projection: M=4096 N=3072 K=1024, 128x64 tiles -> 1536 blocks (R0-exact)
    k_gemm<<<32 * 48, 256, 0, stream>>>(xb, Wqkv, 4096, 3072, 1024, Qb, Kb, Vt);
    // attention: 1024 blocks, longest-first (R0-exact)
    k_attn<<<1024, 256, 0, stream>>>(Qb, Kb, Vt, Ob);
    // output projection: 128x64 tiles -> 512 blocks, dbuf prefetch  [THE CHANGE]
    k_oproj<<<512, 256, 0, stream>>>(Ob, Wpt, bp, out);
}

// Round 7
// 158.725 us; speedup vs baseline: 1.0971x; 1.0295x over previous
//
#include <hip/hip_runtime.h>
#include <hip/hip_bf16.h>

typedef unsigned short u16;
typedef __bf16 bf16x8 __attribute__((ext_vector_type(8)));
typedef float floatx4 __attribute__((ext_vector_type(4)));

#define SB 4
#define ST 1024
#define SC 1024
#define SH 16
#define SD 64

__device__ __forceinline__ u16 f2bf(float f) {
    unsigned int u = __builtin_bit_cast(unsigned int, f);
    u += 0x7fffu + ((u >> 16) & 1u);   // RNE
    return (u16)(u >> 16);
}

// async 16B/lane global->LDS (m97). LDS dest is wave-uniform base + lane*16.
__device__ __forceinline__ void gload16(const u16* g, u16* l) {
    __builtin_amdgcn_global_load_lds(
        (const __attribute__((address_space(1))) unsigned int*)g,
        (__attribute__((address_space(3))) unsigned int*)l, 16, 0, 0);
}

// ---- fused prep: x->bf16 | Wq/Wk/Wv -> Wqkv[n][c] | Wp -> Wpt[n][k] ----
__global__ void k_prep(const float* __restrict__ x,
                       const float* __restrict__ Wq, const float* __restrict__ Wk,
                       const float* __restrict__ Wv, const float* __restrict__ Wp,
                       u16* __restrict__ xb, u16* __restrict__ Wqkv, u16* __restrict__ Wpt) {
    __shared__ float tile[64 * 65];
    const int id = blockIdx.x, tid = threadIdx.x;
    if (id < 4096) {                               // x: fp32 -> bf16, float4 lanes
        int i = id * 256 + tid;
        float4 v = ((const float4*)x)[i];
        uint2 o;
        o.x = (unsigned)f2bf(v.x) | ((unsigned)f2bf(v.y) << 16);
        o.y = (unsigned)f2bf(v.z) | ((unsigned)f2bf(v.w) << 16);
        ((uint2*)xb)[i] = o;
    } else if (id < 4864) {                        // Wq/Wk/Wv transpose to [n][c]
        const int id1 = id - 4096;
        const int qkv = id1 >> 8, rem = id1 & 255, h = rem >> 4, c0 = (rem & 15) * 64;
        const float* src = qkv == 0 ? Wq : (qkv == 1 ? Wk : Wv);
        #pragma unroll
        for (int i = 0; i < 16; ++i) {
            int idx = tid + i * 256;
            int r = idx >> 6, d = idx & 63;
            tile[r * 65 + d] = src[(h * SC + c0 + r) * SD + d];
        }
        __syncthreads();
        #pragma unroll
        for (int i = 0; i < 16; ++i) {
            int idx = tid + i * 256;
            int d = idx >> 6, cc = idx & 63;
            Wqkv[(qkv * 1024 + h * SD + d) * SC + c0 + cc] = f2bf(tile[cc * 65 + d]);
        }
    } else {                                       // Wp transpose to [n][k]
        const int id2 = id - 4864;
        const int n0 = (id2 & 15) * 64, k0 = (id2 >> 4) * 64;
        #pragma unroll
        for (int i = 0; i < 16; ++i) {
            int idx = tid + i * 256;
            int r = idx >> 6, nn = idx & 63;
            tile[r * 65 + nn] = Wp[(k0 + r) * SC + n0 + nn];
        }
        __syncthreads();
        #pragma unroll
        for (int i = 0; i < 16; ++i) {
            int idx = tid + i * 256;
            int nr = idx >> 6, kk = idx & 63;
            Wpt[(n0 + nr) * (SH * SD) + k0 + kk] = f2bf(tile[kk * 65 + nr]);
        }
    }
}

// ---- QKV GEMM: C = A[M,K] * Bt[N,K]^T, bf16, BM=128, BN=64, BK=64 ----
// (R0-exact: best-measured total config)
// Single-barrier prefetch double-buffer. Swapped-operand MFMA -> D^T per-lane:
// m = l16, n = quad*4+r (packed stores).
// Q (pre-scaled by log2e/8) / K -> [bh][t][d]; V -> Vt[bh][d][t].
__launch_bounds__(256)
__global__ void k_gemm(const u16* __restrict__ A, const u16* __restrict__ Bt,
                       int M, int N, int K,
                       u16* __restrict__ Qb, u16* __restrict__ Kb, u16* __restrict__ Vt) {
    constexpr int BM = 128, BN = 64, SM = 4, SN = 2;
    __shared__ u16 Als[2][BM * 64];
    __shared__ u16 Bls[2][BN * 64];
    const int tid = threadIdx.x, lane = tid & 63, w = tid >> 6;
    const int quad = lane >> 4, l16 = lane & 15;
    const int sr = lane >> 3, sc = lane & 7;
    const int nt = N / BN;
    const int m0 = (blockIdx.x / nt) * BM, n0 = (blockIdx.x % nt) * BN;
    const int wm = (w >> 1) * 64, wn = (w & 1) * 32;

    auto stage = [&](int buf, int k0) {
        #pragma unroll
        for (int i = 0; i < 4; ++i) {
            int rb = (w * 4 + i) * 8;
            gload16(&A[(long)(m0 + rb + sr) * K + k0 + ((sc ^ sr) << 3)], &Als[buf][rb * 64]);
        }
        #pragma unroll
        for (int i = 0; i < 2; ++i) {
            int rb = (w * 2 + i) * 8;
            gload16(&Bt[(long)(n0 + rb + sr) * K + k0 + ((sc ^ sr) << 3)], &Bls[buf][rb * 64]);
        }
    };

    floatx4 acc[SM][SN] = {};
    const int niter = K / 64;
    stage(0, 0);
    for (int it = 0; it < niter; ++it) {
        const int buf = it & 1;
        __syncthreads();                       // stage(it) visible + compute(it-1) done
        if (it + 1 < niter) stage(buf ^ 1, (it + 1) * 64);   // flies during compute
        bf16x8 af[SM][2], bfr[SN][2];
        #pragma unroll
        for (int sm = 0; sm < SM; ++sm) {
            int row = wm + sm * 16 + l16;
            #pragma unroll
            for (int ks = 0; ks < 2; ++ks)
                af[sm][ks] = *(const bf16x8*)&Als[buf][row * 64 + (((ks * 4 + quad) ^ (row & 7)) << 3)];
        }
        #pragma unroll
        for (int sn = 0; sn < SN; ++sn) {
            int row = wn + sn * 16 + l16;
            #pragma unroll
            for (int ks = 0; ks < 2; ++ks)
                bfr[sn][ks] = *(const bf16x8*)&Bls[buf][row * 64 + (((ks * 4 + quad) ^ (row & 7)) << 3)];
        }
        #pragma unroll
        for (int ks = 0; ks < 2; ++ks)
            #pragma unroll
            for (int sm = 0; sm < SM; ++sm)
                #pragma unroll
                for (int sn = 0; sn < SN; ++sn)
                    acc[sm][sn] = __builtin_amdgcn_mfma_f32_16x16x32_bf16(bfr[sn][ks], af[sm][ks], acc[sm][sn], 0, 0, 0);
    }
    const int qkv = n0 >> 10, h = (n0 & 1023) >> 6;     // uniform per block
    const float qs = qkv == 0 ? 0.18033688011112042f : 1.0f;  // log2(e)/sqrt(D)
    #pragma unroll
    for (int sm = 0; sm < SM; ++sm) {
        const int m = m0 + wm + sm * 16 + l16;
        const int bb = m >> 10, t = m & 1023;
        #pragma unroll
        for (int sn = 0; sn < SN; ++sn) {
            const int d0 = wn + sn * 16 + (quad << 2);
            u16 pk[4];
            #pragma unroll
            for (int r = 0; r < 4; ++r) pk[r] = f2bf(acc[sm][sn][r] * qs);
            if (qkv == 2) {
                // direct V^T write: Vt[bh][d][t]; lanes share d, consecutive t
                const long vb = (long)(bb * SH + h) * SD * ST + t;
                #pragma unroll
                for (int r = 0; r < 4; ++r) Vt[vb + (long)(d0 + r) * ST] = pk[r];
            } else {
                u16* dst = qkv == 0 ? Qb : Kb;
                *(uint2*)&dst[(((long)(bb * SH + h) * ST + t) << 6) + d0] = *(uint2*)pk;
            }
        }
    }
}

// ---- out-projection: C[4096,1024] = Ob * Wpt^T + bias, BM=BN=64, BK=256 ----
// (R0-exact: confirmed better than 128x64 dbuf by direct A/B, R6 vs R0)
// BK=256 staged as 4 x 64-k sub-tiles (contiguous global_load_lds), single
// buffer: 8 barriers total (vs 32 at BK=64), 32 MFMA/wave per interval.
__launch_bounds__(256)
__global__ void k_oproj(const u16* __restrict__ A, const u16* __restrict__ Bt,
                        const float* __restrict__ bias, float* __restrict__ Cout) {
    constexpr int K = 1024, N = 1024;
    __shared__ u16 Als[4][64 * 64];
    __shared__ u16 Bls[4][64 * 64];
    const int tid = threadIdx.x, lane = tid & 63, w = tid >> 6;
    const int quad = lane >> 4, l16 = lane & 15;
    const int sr = lane >> 3, sc = lane & 7;
    const int m0 = (blockIdx.x >> 4) * 64, n0 = (blockIdx.x & 15) * 64;
    const int wm = (w >> 1) * 32, wn = (w & 1) * 32;

    floatx4 acc[2][2] = {};
    for (int kb = 0; kb < 4; ++kb) {
        const int k0 = kb * 256;
        #pragma unroll
        for (int seg = 0; seg < 4; ++seg) {
            #pragma unroll
            for (int i = 0; i < 2; ++i) {
                int rb = (w * 2 + i) * 8;
                gload16(&A[(long)(m0 + rb + sr) * K + k0 + seg * 64 + ((sc ^ sr) << 3)], &Als[seg][rb * 64]);
                gload16(&Bt[(long)(n0 + rb + sr) * K + k0 + seg * 64 + ((sc ^ sr) << 3)], &Bls[seg][rb * 64]);
            }
        }
        __syncthreads();
        #pragma unroll
        for (int seg = 0; seg < 4; ++seg) {
            bf16x8 af[2][2], bfr[2][2];
            #pragma unroll
            for (int sm = 0; sm < 2; ++sm) {
                int row = wm + sm * 16 + l16;
                #pragma unroll
                for (int ks = 0; ks < 2; ++ks)
                    af[sm][ks] = *(const bf16x8*)&Als[seg][row * 64 + (((ks * 4 + quad) ^ (row & 7)) << 3)];
            }
            #pragma unroll
            for (int sn = 0; sn < 2; ++sn) {
                int row = wn + sn * 16 + l16;
                #pragma unroll
                for (int ks = 0; ks < 2; ++ks)
                    bfr[sn][ks] = *(const bf16x8*)&Bls[seg][row * 64 + (((ks * 4 + quad) ^ (row & 7)) << 3)];
            }
            #pragma unroll
            for (int ks = 0; ks < 2; ++ks)
                #pragma unroll
                for (int sm = 0; sm < 2; ++sm)
                    #pragma unroll
                    for (int sn = 0; sn < 2; ++sn)
                        acc[sm][sn] = __builtin_amdgcn_mfma_f32_16x16x32_bf16(bfr[sn][ks], af[sm][ks], acc[sm][sn], 0, 0, 0);
        }
        if (kb < 3) __syncthreads();           // protect LDS before next stage
    }
    #pragma unroll
    for (int sn = 0; sn < 2; ++sn) {
        const int nb = n0 + wn + sn * 16 + (quad << 2);
        const float4 bv = *(const float4*)&bias[nb];
        #pragma unroll
        for (int sm = 0; sm < 2; ++sm) {
            const int m = m0 + wm + sm * 16 + l16;
            float4 o;
            o.x = acc[sm][sn][0] + bv.x;
            o.y = acc[sm][sn][1] + bv.y;
            o.z = acc[sm][sn][2] + bv.z;
            o.w = acc[sm][sn][3] + bv.w;
            *(float4*)&Cout[(long)m * N + nb] = o;
        }
    }
}

// ---- flash attention: 64-row Q tile/block, prefetch double-buffered K/V ----
// R0 + THE ONE CHANGE: wave-uniform diag-tile skip. On j==tile, wave w's
// rows are [w*16, w*16+16) local, so sn-blocks with sn > w are ENTIRELY
// above the causal diagonal: skip their QK^T MFMAs + exp2 + lsum (37.5%
// of diag softmax work), store zeros to Pls (PV still reads them).
// Branch is wave-uniform (sn compile-time, w wave-uniform, diag block-
// uniform) — no divergence, no LDS/VGPR/occupancy change.
__launch_bounds__(256)
__global__ void k_attn(const u16* __restrict__ Qg, const u16* __restrict__ Kg,
                       const u16* __restrict__ Vtg, u16* __restrict__ Og) {
    __shared__ u16 Kls[2][64 * 64];   // K tile [s][d], XOR-swizzled chunks
    __shared__ u16 Vls[2][64 * 64];   // Vt tile [d][s], XOR-swizzled chunks
    __shared__ u16 Pls[64 * 64];      // P [t_local][s], per-wave 16-row slices
    const int tid = threadIdx.x, lane = tid & 63, w = tid >> 6;
    const int quad = lane >> 4, l16 = lane & 15;
    const int sr = lane >> 3, sc = lane & 7;
    const int tile = 15 - (blockIdx.x >> 6);       // longest tiles dispatch first
    const int bh = blockIdx.x & 63;
    const int t0 = tile * 64;
    const int b = bh >> 4, h = bh & 15;
    const u16* Qbh = Qg + (long)bh * ST * SD;
    const u16* Kbh = Kg + (long)bh * ST * SD;
    const u16* Vbh = Vtg + (long)bh * SD * ST;     // [d][t]

    bf16x8 qf[2];
    {
        const u16* qrow = Qbh + (t0 + w * 16 + l16) * SD;
        qf[0] = *(const bf16x8*)&qrow[quad * 8];
        qf[1] = *(const bf16x8*)&qrow[32 + quad * 8];
    }
    floatx4 oacc[4] = {};
    float lsum = 0.f;
    const int myt = t0 + w * 16 + l16;             // this lane's global t row
    const int rowP = w * 16 + l16;                 // P row (wave-private)

    auto stage = [&](int buf, int s0) {
        #pragma unroll
        for (int i = 0; i < 2; ++i) {
            int rb = (w * 2 + i) * 8;
            gload16(&Kbh[(s0 + rb + sr) * SD + ((sc ^ sr) << 3)], &Kls[buf][rb * 64]);
            gload16(&Vbh[(rb + sr) * ST + s0 + ((sc ^ sr) << 3)], &Vls[buf][rb * 64]);
        }
    };

    stage(0, 0);
    for (int j = 0; j <= tile; ++j) {
        const int buf = j & 1;
        const int s0 = j * 64;
        __syncthreads();                           // stage(j) visible + compute(j-1) done
        if (j < tile) stage(buf ^ 1, s0 + 64);     // flies during compute

        const bool diag = (j == tile);
        // S^T = (Q K^T)^T : mfma(K-frag, Q-frag) -> s = quad*4+r, t = l16
        // diag: sn > w is fully above the causal diagonal -> skip (wave-uniform)
        floatx4 sa[4] = {};
        #pragma unroll
        for (int sn = 0; sn < 4; ++sn) {
            if (diag && sn > w) continue;
            int row = sn * 16 + l16;
            #pragma unroll
            for (int ks = 0; ks < 2; ++ks) {
                bf16x8 kf = *(const bf16x8*)&Kls[buf][row * 64 + (((ks * 4 + quad) ^ (row & 7)) << 3)];
                sa[sn] = __builtin_amdgcn_mfma_f32_16x16x32_bf16(kf, qf[ks], sa[sn], 0, 0, 0);
            }
        }
        #pragma unroll
        for (int sn = 0; sn < 4; ++sn) {
            const int sl = sn * 16 + (quad << 2);
            u16 pk[4];
            if (diag && sn > w) {                  // fully masked: store zeros only
                pk[0] = pk[1] = pk[2] = pk[3] = 0;
            } else {
                #pragma unroll
                for (int r = 0; r < 4; ++r) {
                    float e = __builtin_exp2f(sa[sn][r]);
                    if (diag && s0 + sl + r > myt) e = 0.f;
                    lsum += e;
                    pk[r] = (u16)(__builtin_bit_cast(unsigned int, e) >> 16);  // trunc, e>=0
                }
            }
            *(uint2*)&Pls[rowP * 64 + (((sl >> 3) ^ (rowP & 7)) << 3) + ((quad & 1) << 2)] = *(uint2*)pk;
        }
        // P rows wave-private: lgkmcnt covers RAW, no barrier
        bf16x8 pf[2];
        #pragma unroll
        for (int ks = 0; ks < 2; ++ks)
            pf[ks] = *(const bf16x8*)&Pls[rowP * 64 + (((ks * 4 + quad) ^ (rowP & 7)) << 3)];
        // O^T += (P V)^T : mfma(Vt-frag, P-frag) -> d = quad*4+r, t = l16
        #pragma unroll
        for (int dn = 0; dn < 4; ++dn) {
            int row = dn * 16 + l16;
            #pragma unroll
            for (int ks = 0; ks < 2; ++ks) {
                bf16x8 vf = *(const bf16x8*)&Vls[buf][row * 64 + (((ks * 4 + quad) ^ (row & 7)) << 3)];
                oacc[dn] = __builtin_amdgcn_mfma_f32_16x16x32_bf16(vf, pf[ks], oacc[dn], 0, 0, 0);
            }
        }
    }
    // per-lane row sum: reduce the 4 quads (same t = l16)
    float l = lsum;
    l += __shfl_xor(l, 16);
    l += __shfl_xor(l, 32);
    const float inv = 1.0f / l;
    const long obase = ((long)(b * ST + myt) << 10) + h * SD;
    #pragma unroll
    for (int dn = 0; dn < 4; ++dn) {
        u16 pk[4];
        #pragma unroll
        for (int r = 0; r < 4; ++r) pk[r] = f2bf(oacc[dn][r] * inv);
        *(uint2*)&Og[obase + dn * 16 + (quad << 2)] = *(uint2*)pk;
    }
}

extern "C" void kernel_launch(void* const* d_in, const int* in_sizes, int n_in,
                              void* d_out, int out_size, void* d_ws, size_t ws_size,
                              hipStream_t stream) {
    const float* x  = (const float*)d_in[0];
    const float* Wq = (const float*)d_in[1];
    const float* Wk = (const float*)d_in[2];
    const float* Wv = (const float*)d_in[3];
    const float* Wp = (const float*)d_in[4];
    const float* bp = (const float*)d_in[5];
    float* out = (float*)d_out;

    char* ws = (char*)d_ws;                       // 48 MB used
    u16* xb   = (u16*)(ws);                       // [4096][1024]   8 MB
    u16* Wqkv = (u16*)(ws + (8ll  << 20));        // [3072][1024]   6 MB
    u16* Wpt  = (u16*)(ws + (14ll << 20));        // [1024][1024]   2 MB
    u16* Qb   = (u16*)(ws + (16ll << 20));        // [64][1024][64] 8 MB
    u16* Kb   = (u16*)(ws + (24ll << 20));        // 8 MB
    u16* Vt   = (u16*)(ws + (32ll << 20));        // [64][64][1024] 8 MB
    u16* Ob   = (u16*)(ws + (40ll << 20));        // [4096][1024]   8 MB

    // fused conversions: 4096 (x) + 768 (Wqkv) + 256 (Wp) blocks
    k_prep<<<5120, 256, 0, stream>>>(x, Wq, Wk, Wv, Wp, xb, Wqkv, Wpt);
    // QKV projection: M=4096 N=3072 K=1024, 128x64 tiles -> 1536 blocks (R0-exact)
    k_gemm<<<32 * 48, 256, 0, stream>>>(xb, Wqkv, 4096, 3072, 1024, Qb, Kb, Vt);
    // attention: 1024 blocks, longest-first (R0 + diag-skip)  [THE CHANGE]
    k_attn<<<1024, 256, 0, stream>>>(Qb, Kb, Vt, Ob);
    // output projection: 64x64 tiles, BK=256 -> 1024 blocks, 8 barriers (R0-exact)
    k_oproj<<<1024, 256, 0, stream>>>(Ob, Wpt, bp, out);
}